// Round 2
// baseline (92.259 us; speedup 1.0000x reference)
//
#include <hip/hip_runtime.h>
#include <hip/hip_bf16.h>

// IDW, POWER=2.0 -> w = 1/d2 (sqrt cancels). out = sum(w*v)/sum(w).
// B=2, P=131072, S=512. One thread per (b,p).
// R2: stations staged in LDS as float4{x,y,v,_} (8 KB), broadcast ds_read_b128
// (all lanes same addr -> conflict-free). Pairwise rcp combine halves the
// quarter-rate v_rcp_f32 count: 1/a+1/b=(a+b)*rcp(ab). ~20 cyc/station/wave VALU.

#define BLOCK 256
#define S_MAX 512

__global__ __launch_bounds__(BLOCK) void idw_kernel(
    const float* __restrict__ station_coords,  // (B, S, 2)
    const float* __restrict__ station_values,  // (B, S)
    const float* __restrict__ grid_points,     // (B, P, 2)
    float* __restrict__ out,                   // (B, P)
    int P, int S) {

    __shared__ float4 st[S_MAX];

    const int b = blockIdx.y;
    const float2* __restrict__ sc2 = (const float2*)(station_coords) + (size_t)b * S;
    const float*  __restrict__ svb = station_values + (size_t)b * S;

    // Stage stations: packed (x, y, value, pad) -> one ds_read_b128 per station.
    for (int i = threadIdx.x; i < S; i += BLOCK) {
        const float2 c = sc2[i];
        st[i] = make_float4(c.x, c.y, svb[i], 0.0f);
    }
    __syncthreads();

    const int p = blockIdx.x * BLOCK + threadIdx.x;
    if (p >= P) return;  // P is an exact multiple of BLOCK; no divergence in practice

    const float2 g = ((const float2*)grid_points)[(size_t)b * P + p];
    const float gx = g.x, gy = g.y;

    constexpr float EPS  = 1.1920928955078125e-07f;
    constexpr float EPS2 = EPS * EPS;  // ref: dist==0 -> EPS -> w = 1/EPS^2

    float wsum = 0.0f;
    float vsum = 0.0f;

#pragma unroll 8
    for (int s = 0; s < S; s += 2) {
        const float4 s0 = st[s];
        const float4 s1 = st[s + 1];

        const float dx0 = gx - s0.x, dy0 = gy - s0.y;
        float a = fmaf(dx0, dx0, dy0 * dy0);
        a = fmaxf(a, EPS2);

        const float dx1 = gx - s1.x, dy1 = gy - s1.y;
        float bq = fmaf(dx1, dx1, dy1 * dy1);
        bq = fmaxf(bq, EPS2);

        // 1/a + 1/b = (a+b)*rcp(ab);  v0/a + v1/b = (v0*b + v1*a)*rcp(ab)
        const float ab = a * bq;
        const float r  = __builtin_amdgcn_rcpf(ab);
        wsum = fmaf(a + bq, r, wsum);
        const float m    = s0.z * bq;
        const float vnum = fmaf(s1.z, a, m);
        vsum = fmaf(vnum, r, vsum);
    }

    out[(size_t)b * P + p] = vsum / wsum;  // one precise div per thread
}

extern "C" void kernel_launch(void* const* d_in, const int* in_sizes, int n_in,
                              void* d_out, int out_size, void* d_ws, size_t ws_size,
                              hipStream_t stream) {
    const float* station_coords = (const float*)d_in[0];
    const float* station_values = (const float*)d_in[1];
    const float* grid_points    = (const float*)d_in[2];
    float* out = (float*)d_out;

    const int B = 2;
    const int S = in_sizes[1] / B;   // 512
    const int P = out_size / B;      // 131072

    dim3 grid((P + BLOCK - 1) / BLOCK, B);
    dim3 block(BLOCK);
    idw_kernel<<<grid, block, 0, stream>>>(station_coords, station_values,
                                           grid_points, out, P, S);
}

// Round 3
// 87.036 us; speedup vs baseline: 1.0600x; 1.0600x over previous
//
#include <hip/hip_runtime.h>
#include <hip/hip_bf16.h>

// IDW, POWER=2.0 -> w = 1/d2 (sqrt cancels). out = sum(w*v)/sum(w).
// B=2, P=131072, S=512.
// R3: G=2 grid points per thread (halves LDS-pipe cycles per station-point),
// stations packed 12B AoS {x,y,v} in LDS -> 4 stations per 3x ds_read_b128
// (broadcast, conflict-free). Pairwise rcp combine: 1/a+1/b=(a+b)*rcp(ab).
// Model: VALU ~17us, LDS ~15us, 2 waves/SIMD -> VALU-bound ~21-24us.

#define BLOCK 256
#define S_MAX 512
#define GPT 2  // grid points per thread

__global__ __launch_bounds__(BLOCK) void idw_kernel(
    const float* __restrict__ station_coords,  // (B, S, 2)
    const float* __restrict__ station_values,  // (B, S)
    const float* __restrict__ grid_points,     // (B, P, 2)
    float* __restrict__ out,                   // (B, P)
    int P, int S) {

    __shared__ float st[S_MAX * 3];  // packed {x,y,v} per station, 12B stride

    const int b = blockIdx.y;
    const float2* __restrict__ sc2 = (const float2*)(station_coords) + (size_t)b * S;
    const float*  __restrict__ svb = station_values + (size_t)b * S;

    for (int i = threadIdx.x; i < S; i += BLOCK) {
        const float2 c = sc2[i];
        st[3 * i + 0] = c.x;
        st[3 * i + 1] = c.y;
        st[3 * i + 2] = svb[i];
    }
    __syncthreads();

    // Thread handles points {2*tid, 2*tid+1} of batch b. Grid sized exactly.
    const int tid = blockIdx.x * BLOCK + threadIdx.x;
    const float4 g01 = ((const float4*)grid_points)[(size_t)b * (P / 2) + tid];
    const float gx0 = g01.x, gy0 = g01.y, gx1 = g01.z, gy1 = g01.w;

    constexpr float EPS  = 1.1920928955078125e-07f;
    constexpr float EPS2 = EPS * EPS;  // ref: dist==0 -> EPS -> w = 1/EPS^2

    float wsum0 = 0.0f, vsum0 = 0.0f;
    float wsum1 = 0.0f, vsum1 = 0.0f;

    const float4* __restrict__ st4 = (const float4*)st;

    // Station pair (ax,ay,av)+(bx,by,bv) applied to both grid points.
    auto do_pair = [&](float ax, float ay, float av,
                       float bx, float by, float bv) {
        // point 0
        {
            const float dxa = gx0 - ax, dya = gy0 - ay;
            float a = fmaf(dxa, dxa, dya * dya);
            a = fmaxf(a, EPS2);
            const float dxb = gx0 - bx, dyb = gy0 - by;
            float bq = fmaf(dxb, dxb, dyb * dyb);
            bq = fmaxf(bq, EPS2);
            const float r = __builtin_amdgcn_rcpf(a * bq);
            wsum0 = fmaf(a + bq, r, wsum0);
            vsum0 = fmaf(fmaf(bv, a, av * bq), r, vsum0);
        }
        // point 1
        {
            const float dxa = gx1 - ax, dya = gy1 - ay;
            float a = fmaf(dxa, dxa, dya * dya);
            a = fmaxf(a, EPS2);
            const float dxb = gx1 - bx, dyb = gy1 - by;
            float bq = fmaf(dxb, dxb, dyb * dyb);
            bq = fmaxf(bq, EPS2);
            const float r = __builtin_amdgcn_rcpf(a * bq);
            wsum1 = fmaf(a + bq, r, wsum1);
            vsum1 = fmaf(fmaf(bv, a, av * bq), r, vsum1);
        }
    };

#pragma unroll 4
    for (int k = 0; k < S_MAX / 4; ++k) {
        const float4 f0 = st4[3 * k + 0];  // x0 y0 v0 x1
        const float4 f1 = st4[3 * k + 1];  // y1 v1 x2 y2
        const float4 f2 = st4[3 * k + 2];  // v2 x3 y3 v3
        do_pair(f0.x, f0.y, f0.z, f0.w, f1.x, f1.y);
        do_pair(f1.z, f1.w, f2.x, f2.y, f2.z, f2.w);
    }

    const float r0 = vsum0 / wsum0;
    const float r1 = vsum1 / wsum1;
    ((float2*)out)[(size_t)b * (P / 2) + tid] = make_float2(r0, r1);
}

extern "C" void kernel_launch(void* const* d_in, const int* in_sizes, int n_in,
                              void* d_out, int out_size, void* d_ws, size_t ws_size,
                              hipStream_t stream) {
    const float* station_coords = (const float*)d_in[0];
    const float* station_values = (const float*)d_in[1];
    const float* grid_points    = (const float*)d_in[2];
    float* out = (float*)d_out;

    const int B = 2;
    const int S = in_sizes[1] / B;   // 512
    const int P = out_size / B;      // 131072

    dim3 grid(P / (BLOCK * GPT), B);  // 256 x 2 = 512 blocks
    dim3 block(BLOCK);
    idw_kernel<<<grid, block, 0, stream>>>(station_coords, station_values,
                                           grid_points, out, P, S);
}

// Round 4
// 84.386 us; speedup vs baseline: 1.0933x; 1.0314x over previous
//
#include <hip/hip_runtime.h>
#include <hip/hip_bf16.h>

// IDW, POWER=2.0 -> w = 1/d2 (sqrt cancels). out = sum(w*v)/sum(w).
// B=2, P=131072, S=512.
// R4: (a) packed fp32 — two grid points per <2 x float> lane pair so the
//     backend emits v_pk_{sub,mul,fma,max}_f32 (MI355X's 157 TF fp32 is
//     packed-only; scalar VALU is half rate). (b) GPT=4 points/thread:
//     LDS ds_read_b128 count per station-point halves vs GPT=2 -> LDS pipe
//     ~7.7us, packed VALU ~10.2us, 256 blocks = exactly 1 block/CU.
// Pairwise rcp combine: 1/a+1/b=(a+b)*rcp(ab) (halves quarter-rate v_rcp).

typedef float v2f __attribute__((ext_vector_type(2)));

#define BLOCK 256
#define S_MAX 512
#define GPT 4

static __device__ __forceinline__ v2f vfma(v2f a, v2f b, v2f c) {
#if __has_builtin(__builtin_elementwise_fma)
    return __builtin_elementwise_fma(a, b, c);
#else
    v2f r; r.x = fmaf(a.x, b.x, c.x); r.y = fmaf(a.y, b.y, c.y); return r;
#endif
}
static __device__ __forceinline__ v2f vmax(v2f a, v2f b) {
#if __has_builtin(__builtin_elementwise_max)
    return __builtin_elementwise_max(a, b);
#else
    v2f r; r.x = fmaxf(a.x, b.x); r.y = fmaxf(a.y, b.y); return r;
#endif
}
static __device__ __forceinline__ v2f splat(float s) { v2f r = {s, s}; return r; }

__global__ __launch_bounds__(BLOCK) void idw_kernel(
    const float* __restrict__ station_coords,  // (B, S, 2)
    const float* __restrict__ station_values,  // (B, S)
    const float* __restrict__ grid_points,     // (B, P, 2)
    float* __restrict__ out,                   // (B, P)
    int P, int S) {

    __shared__ float st[S_MAX * 3];  // packed {x,y,v}, 12B/station

    const int b = blockIdx.y;
    const float2* __restrict__ sc2 = (const float2*)(station_coords) + (size_t)b * S;
    const float*  __restrict__ svb = station_values + (size_t)b * S;

    for (int i = threadIdx.x; i < S; i += BLOCK) {
        const float2 c = sc2[i];
        st[3 * i + 0] = c.x;
        st[3 * i + 1] = c.y;
        st[3 * i + 2] = svb[i];
    }
    __syncthreads();

    // Thread handles 4 consecutive points: 4*tid .. 4*tid+3 of batch b.
    const int tid = blockIdx.x * BLOCK + threadIdx.x;
    const float4* __restrict__ gp =
        (const float4*)(grid_points + (size_t)b * P * 2);
    const float4 gA = gp[2 * tid + 0];  // x0 y0 x1 y1
    const float4 gB = gp[2 * tid + 1];  // x2 y2 x3 y3
    const v2f gx01 = {gA.x, gA.z}, gy01 = {gA.y, gA.w};
    const v2f gx23 = {gB.x, gB.z}, gy23 = {gB.y, gB.w};

    constexpr float EPS  = 1.1920928955078125e-07f;
    const v2f eps2 = splat(EPS * EPS);  // ref: dist==0 -> EPS -> w = 1/EPS^2

    v2f wsum01 = {0.f, 0.f}, vsum01 = {0.f, 0.f};
    v2f wsum23 = {0.f, 0.f}, vsum23 = {0.f, 0.f};

    const float4* __restrict__ st4 = (const float4*)st;

    // Station pair (A,B) applied to one packed point-pair.
    auto do_pair = [&](v2f gx, v2f gy, v2f& wsum, v2f& vsum,
                       float ax, float ay, float av,
                       float bx, float by, float bv) {
        const v2f dxa = gx - ax, dya = gy - ay;          // pk sub x2
        v2f a = vfma(dxa, dxa, dya * dya);               // pk mul + pk fma
        a = vmax(a, eps2);                               // pk max
        const v2f dxb = gx - bx, dyb = gy - by;
        v2f bb = vfma(dxb, dxb, dyb * dyb);
        bb = vmax(bb, eps2);
        const v2f ab = a * bb;                           // pk mul
        v2f r;                                           // 2x scalar v_rcp_f32
        r.x = __builtin_amdgcn_rcpf(ab.x);
        r.y = __builtin_amdgcn_rcpf(ab.y);
        wsum = vfma(a + bb, r, wsum);                    // pk add + pk fma
        const v2f vnum = vfma(splat(bv), a, splat(av) * bb);  // pk mul + pk fma
        vsum = vfma(vnum, r, vsum);                      // pk fma
    };

#pragma unroll 4
    for (int k = 0; k < S_MAX / 4; ++k) {
        const float4 f0 = st4[3 * k + 0];  // Ax Ay Av Bx
        const float4 f1 = st4[3 * k + 1];  // By Bv Cx Cy
        const float4 f2 = st4[3 * k + 2];  // Cv Dx Dy Dv
        do_pair(gx01, gy01, wsum01, vsum01, f0.x, f0.y, f0.z, f0.w, f1.x, f1.y);
        do_pair(gx23, gy23, wsum23, vsum23, f0.x, f0.y, f0.z, f0.w, f1.x, f1.y);
        do_pair(gx01, gy01, wsum01, vsum01, f1.z, f1.w, f2.x, f2.y, f2.z, f2.w);
        do_pair(gx23, gy23, wsum23, vsum23, f1.z, f1.w, f2.x, f2.y, f2.z, f2.w);
    }

    float4 res;
    res.x = vsum01.x / wsum01.x;
    res.y = vsum01.y / wsum01.y;
    res.z = vsum23.x / wsum23.x;
    res.w = vsum23.y / wsum23.y;
    ((float4*)out)[(size_t)b * (P / 4) + tid] = res;
}

extern "C" void kernel_launch(void* const* d_in, const int* in_sizes, int n_in,
                              void* d_out, int out_size, void* d_ws, size_t ws_size,
                              hipStream_t stream) {
    const float* station_coords = (const float*)d_in[0];
    const float* station_values = (const float*)d_in[1];
    const float* grid_points    = (const float*)d_in[2];
    float* out = (float*)d_out;

    const int B = 2;
    const int S = in_sizes[1] / B;   // 512
    const int P = out_size / B;      // 131072

    dim3 grid(P / (BLOCK * GPT), B);  // 128 x 2 = 256 blocks = 1 per CU
    dim3 block(BLOCK);
    idw_kernel<<<grid, block, 0, stream>>>(station_coords, station_values,
                                           grid_points, out, P, S);
}

// Round 5
// 81.368 us; speedup vs baseline: 1.1339x; 1.0371x over previous
//
#include <hip/hip_runtime.h>
#include <hip/hip_bf16.h>

// IDW, POWER=2.0 -> w = 1/d2 (sqrt cancels). out = sum(w*v)/sum(w).
// B=2, P=131072, S=512.
// R5: GPT=2 (2 waves/SIMD — TLP to overlap VALU and LDS pipes; R4's GPT=4
//     at 1 wave/SIMD serialized them). Scalar fp32 (pk_fma_f32 is half-rate
//     on CDNA4 — 157 TF spec IS the scalar rate; packing gains nothing).
//     EPS folded into the fma chain: d2 = fma(dx,dx, fma(dy,dy,EPS2)) —
//     drops fmax+mul, exact at d2==0 (w -> 1/EPS^2 like ref).
//     Pairwise rcp: 1/a+1/b = (a+b)*rcp(ab). 7.5 VALU + 0.5 rcp per
//     station-point -> ~19 cyc/station-point-wave -> VALU floor ~16 us.

#define BLOCK 256
#define S_MAX 512
#define GPT 2

__global__ __launch_bounds__(BLOCK) void idw_kernel(
    const float* __restrict__ station_coords,  // (B, S, 2)
    const float* __restrict__ station_values,  // (B, S)
    const float* __restrict__ grid_points,     // (B, P, 2)
    float* __restrict__ out,                   // (B, P)
    int P, int S) {

    __shared__ float st[S_MAX * 3];  // packed {x,y,v}, 12B/station

    const int b = blockIdx.y;
    const float2* __restrict__ sc2 = (const float2*)(station_coords) + (size_t)b * S;
    const float*  __restrict__ svb = station_values + (size_t)b * S;

    for (int i = threadIdx.x; i < S; i += BLOCK) {
        const float2 c = sc2[i];
        st[3 * i + 0] = c.x;
        st[3 * i + 1] = c.y;
        st[3 * i + 2] = svb[i];
    }
    __syncthreads();

    // Thread handles points {2*tid, 2*tid+1} of batch b; grid sized exactly.
    const int tid = blockIdx.x * BLOCK + threadIdx.x;
    const float4 g01 = ((const float4*)grid_points)[(size_t)b * (P / 2) + tid];
    const float gx0 = g01.x, gy0 = g01.y, gx1 = g01.z, gy1 = g01.w;

    constexpr float EPS  = 1.1920928955078125e-07f;
    constexpr float EPS2 = EPS * EPS;

    float wsum0 = 0.0f, vsum0 = 0.0f;
    float wsum1 = 0.0f, vsum1 = 0.0f;

    const float4* __restrict__ st4 = (const float4*)st;

    // Two stations (A,B) against one point: 15 plain VALU + 1 rcp.
    auto pair2 = [&](float gx, float gy, float& ws, float& vs,
                     float ax, float ay, float av,
                     float bx, float by, float bv) {
        const float dxa = gx - ax, dya = gy - ay;
        const float a = fmaf(dxa, dxa, fmaf(dya, dya, EPS2));
        const float dxb = gx - bx, dyb = gy - by;
        const float bq = fmaf(dxb, dxb, fmaf(dyb, dyb, EPS2));
        const float r = __builtin_amdgcn_rcpf(a * bq);
        ws = fmaf(a + bq, r, ws);
        vs = fmaf(fmaf(bv, a, av * bq), r, vs);
    };

#pragma unroll 4
    for (int k = 0; k < S_MAX / 4; ++k) {
        const float4 f0 = st4[3 * k + 0];  // Ax Ay Av Bx
        const float4 f1 = st4[3 * k + 1];  // By Bv Cx Cy
        const float4 f2 = st4[3 * k + 2];  // Cv Dx Dy Dv
        pair2(gx0, gy0, wsum0, vsum0, f0.x, f0.y, f0.z, f0.w, f1.x, f1.y);
        pair2(gx1, gy1, wsum1, vsum1, f0.x, f0.y, f0.z, f0.w, f1.x, f1.y);
        pair2(gx0, gy0, wsum0, vsum0, f1.z, f1.w, f2.x, f2.y, f2.z, f2.w);
        pair2(gx1, gy1, wsum1, vsum1, f1.z, f1.w, f2.x, f2.y, f2.z, f2.w);
    }

    const float r0 = vsum0 / wsum0;
    const float r1 = vsum1 / wsum1;
    ((float2*)out)[(size_t)b * (P / 2) + tid] = make_float2(r0, r1);
}

extern "C" void kernel_launch(void* const* d_in, const int* in_sizes, int n_in,
                              void* d_out, int out_size, void* d_ws, size_t ws_size,
                              hipStream_t stream) {
    const float* station_coords = (const float*)d_in[0];
    const float* station_values = (const float*)d_in[1];
    const float* grid_points    = (const float*)d_in[2];
    float* out = (float*)d_out;

    const int B = 2;
    const int S = in_sizes[1] / B;   // 512
    const int P = out_size / B;      // 131072

    dim3 grid(P / (BLOCK * GPT), B);  // 256 x 2 = 512 blocks, 2 per CU
    dim3 block(BLOCK);
    idw_kernel<<<grid, block, 0, stream>>>(station_coords, station_values,
                                           grid_points, out, P, S);
}

// Round 6
// 79.668 us; speedup vs baseline: 1.1580x; 1.0213x over previous
//
#include <hip/hip_runtime.h>
#include <hip/hip_bf16.h>

// IDW, POWER=2.0 -> w = 1/d2 (sqrt cancels). out = sum(w*v)/sum(w).
// B=2, P=131072, S=512.
// R6: (a) manual 1-chunk software pipeline: ds_read next 4-station chunk into
//     rotation regs BEFORE computing current chunk -> LDS latency (~150cyc)
//     hidden under ~280cyc compute; R5 showed LDS+VALU fully serialized
//     (31us = 15.4+16.2) because compiler didn't prefetch (VGPR=36).
// (b) 4-way rcp combine: 1/a+1/b+1/c+1/d = (sAB*pCD + sCD*pAB)*rcp(pAB*pCD);
//     31 plain + 1 rcp per 4 stations/point (vs 30+2) -> VALU ~14.9us.
// (c) GPT=2, 512 blocks (2/CU, 2 waves/SIMD) for TLP overlap margin.
// EPS2 folded into the d2 fma chain (exact at d2==0: w -> 1/EPS^2 like ref).

#define BLOCK 256
#define S_MAX 512
#define GPT 2

__global__ __launch_bounds__(BLOCK) void idw_kernel(
    const float* __restrict__ station_coords,  // (B, S, 2)
    const float* __restrict__ station_values,  // (B, S)
    const float* __restrict__ grid_points,     // (B, P, 2)
    float* __restrict__ out,                   // (B, P)
    int P, int S) {

    __shared__ float st[S_MAX * 3];  // packed {x,y,v}, 12B/station

    const int b = blockIdx.y;
    const float2* __restrict__ sc2 = (const float2*)(station_coords) + (size_t)b * S;
    const float*  __restrict__ svb = station_values + (size_t)b * S;

    for (int i = threadIdx.x; i < S; i += BLOCK) {
        const float2 c = sc2[i];
        st[3 * i + 0] = c.x;
        st[3 * i + 1] = c.y;
        st[3 * i + 2] = svb[i];
    }
    __syncthreads();

    const int tid = blockIdx.x * BLOCK + threadIdx.x;
    const float4 g01 = ((const float4*)grid_points)[(size_t)b * (P / 2) + tid];
    const float gx0 = g01.x, gy0 = g01.y, gx1 = g01.z, gy1 = g01.w;

    constexpr float EPS  = 1.1920928955078125e-07f;
    constexpr float EPS2 = EPS * EPS;

    float wsum0 = 0.0f, vsum0 = 0.0f;
    float wsum1 = 0.0f, vsum1 = 0.0f;

    const float4* __restrict__ st4 = (const float4*)st;

    // 4 stations A,B,C,D vs one point: 31 plain VALU + 1 rcp.
    // layout: f0 = Ax Ay Av Bx | f1 = By Bv Cx Cy | f2 = Cv Dx Dy Dv
    auto quad = [&](float gx, float gy, float& ws, float& vs,
                    const float4& f0, const float4& f1, const float4& f2) {
        const float dxa = gx - f0.x, dya = gy - f0.y;
        const float a = fmaf(dxa, dxa, fmaf(dya, dya, EPS2));
        const float dxb = gx - f0.w, dyb = gy - f1.x;
        const float bq = fmaf(dxb, dxb, fmaf(dyb, dyb, EPS2));
        const float dxc = gx - f1.z, dyc = gy - f1.w;
        const float c = fmaf(dxc, dxc, fmaf(dyc, dyc, EPS2));
        const float dxd = gx - f2.y, dyd = gy - f2.z;
        const float d = fmaf(dxd, dxd, fmaf(dyd, dyd, EPS2));
        const float pab = a * bq, pcd = c * d;
        const float sab = a + bq, scd = c + d;
        const float nab = fmaf(f1.y, a, f0.z * bq);  // vB*a + vA*b
        const float ncd = fmaf(f2.w, c, f2.x * d);   // vD*c + vC*d
        const float r = __builtin_amdgcn_rcpf(pab * pcd);
        ws = fmaf(fmaf(sab, pcd, scd * pab), r, ws);
        vs = fmaf(fmaf(nab, pcd, ncd * pab), r, vs);
    };

    // Software pipeline: prefetch chunk k+1 while computing chunk k.
    float4 c0 = st4[0], c1 = st4[1], c2 = st4[2];
#pragma unroll 4
    for (int k = 0; k < S_MAX / 4 - 1; ++k) {
        const float4 n0 = st4[3 * k + 3];
        const float4 n1 = st4[3 * k + 4];
        const float4 n2 = st4[3 * k + 5];
        quad(gx0, gy0, wsum0, vsum0, c0, c1, c2);
        quad(gx1, gy1, wsum1, vsum1, c0, c1, c2);
        c0 = n0; c1 = n1; c2 = n2;
    }
    quad(gx0, gy0, wsum0, vsum0, c0, c1, c2);
    quad(gx1, gy1, wsum1, vsum1, c0, c1, c2);

    const float r0 = vsum0 / wsum0;
    const float r1 = vsum1 / wsum1;
    ((float2*)out)[(size_t)b * (P / 2) + tid] = make_float2(r0, r1);
}

extern "C" void kernel_launch(void* const* d_in, const int* in_sizes, int n_in,
                              void* d_out, int out_size, void* d_ws, size_t ws_size,
                              hipStream_t stream) {
    const float* station_coords = (const float*)d_in[0];
    const float* station_values = (const float*)d_in[1];
    const float* grid_points    = (const float*)d_in[2];
    float* out = (float*)d_out;

    const int B = 2;
    const int S = in_sizes[1] / B;   // 512
    const int P = out_size / B;      // 131072

    dim3 grid(P / (BLOCK * GPT), B);  // 256 x 2 = 512 blocks, 2 per CU
    dim3 block(BLOCK);
    idw_kernel<<<grid, block, 0, stream>>>(station_coords, station_values,
                                           grid_points, out, P, S);
}